// Round 1
// baseline (158.512 us; speedup 1.0000x reference)
//
#include <hip/hip_runtime.h>
#include <hip/hip_fp16.h>

#define B_N 1024
#define D_K 128
#define C_N 100000
#define CCHUNK 80            // 1250 * 80 == 100000 exactly, multiple of 16
#define NBLK_MAIN 1250
#define EPSN 1e-12f

typedef _Float16 half8 __attribute__((ext_vector_type(8)));
typedef float floatx4 __attribute__((ext_vector_type(4)));

union U16 { uint4 u; half8 h; };

__device__ __forceinline__ unsigned int pack2h(float a, float b) {
    union { _Float16 h[2]; unsigned int u; } p;
    p.h[0] = (_Float16)a; p.h[1] = (_Float16)b;
    return p.u;
}

// ---------------------------------------------------------------------------
// Prep: per-row ||x||^2, w[b]=exp(-||x||^2-1), xs -> fp16 fragment-order,
// exact fp32 positive distance posd[b], zero negsum. One wave per row b.
// ---------------------------------------------------------------------------
__global__ __launch_bounds__(256) void prep_kernel(
    const float* __restrict__ xs, const int* __restrict__ ys,
    const float* __restrict__ proxies,
    unsigned int* __restrict__ xfrag, float* __restrict__ w,
    float* __restrict__ posd, float* __restrict__ negsum)
{
    int tid  = threadIdx.x;
    int gid  = blockIdx.x * 256 + tid;
    if (gid < B_N) negsum[gid] = 0.0f;

    int wave = tid >> 6, lane = tid & 63;
    int b = blockIdx.x * 4 + wave;   // grid = 256 blocks -> b in [0,1024)

    const float2 xv = ((const float2*)(xs + (size_t)b * D_K))[lane];
    float ss = xv.x * xv.x + xv.y * xv.y;
    #pragma unroll
    for (int m = 1; m < 64; m <<= 1) ss += __shfl_xor(ss, m, 64);
    float xsq = ss;

    // fragment-order write: element (b, k=2*lane, 2*lane+1)
    // slot: tile bt=b>>4, frag f=k>>5, lane_slot=(b&15)|(((k>>3)&3)<<4), uint j=(k&7)>>1
    {
        int f  = lane >> 4;
        int m4 = (lane >> 2) & 3;
        int j  = lane & 3;
        int idx = ((((b >> 4) * 4 + f) * 64) + ((b & 15) | (m4 << 4))) * 4 + j;
        xfrag[idx] = pack2h(xv.x, xv.y);
    }

    // positive proxy: exact fp32 dot + norm
    int y = ys[b];
    const float2 pv = ((const float2*)(proxies + (size_t)y * D_K))[lane];
    float dt = xv.x * pv.x + xv.y * pv.y;
    float pp = pv.x * pv.x + pv.y * pv.y;
    #pragma unroll
    for (int m = 1; m < 64; m <<= 1) {
        dt += __shfl_xor(dt, m, 64);
        pp += __shfl_xor(pp, m, 64);
    }
    if (lane == 0) {
        w[b] = __expf(-xsq - 1.0f);
        float nrm = fmaxf(sqrtf(pp), EPSN);
        posd[b] = xsq + 1.0f - 2.0f * (dt / nrm);
    }
}

// ---------------------------------------------------------------------------
// Main: each block handles 80 proxies (normalize->fp16->LDS in A-frag order),
// all 1024 samples. Wave w owns b in [w*256, w*256+256).
// S[c][b] via mfma_f32_16x16x32_f16 (A = proxy tile, B = x tile),
// accumulate sum_c exp(2*S) per b, scale by w[b], atomicAdd into negsum.
// ---------------------------------------------------------------------------
__global__ __launch_bounds__(256, 2) void main_kernel(
    const float* __restrict__ proxies,
    const uint4* __restrict__ xfrag,
    const float* __restrict__ w,
    float* __restrict__ negsum)
{
    __shared__ uint4 ldsP[CCHUNK * 8];   // 80 rows * 128 k * 2B = 1280 uint4 = 20 KB

    int tid = threadIdx.x;
    int c0  = blockIdx.x * CCHUNK;

    // ---- stage + normalize: 8 lanes per row, 32 rows per pass ----
    {
        int L  = tid & 7;        // lane within row: covers k = L*16 .. L*16+15
        int rb = tid >> 3;       // 0..31
        #pragma unroll 1
        for (int pass = 0; pass < 3; ++pass) {
            int r = pass * 32 + rb;
            if (r < CCHUNK) {
                const float4* src = (const float4*)(proxies + (size_t)(c0 + r) * D_K + L * 16);
                float4 v0 = src[0], v1 = src[1], v2 = src[2], v3 = src[3];
                float ss = v0.x*v0.x + v0.y*v0.y + v0.z*v0.z + v0.w*v0.w
                         + v1.x*v1.x + v1.y*v1.y + v1.z*v1.z + v1.w*v1.w
                         + v2.x*v2.x + v2.y*v2.y + v2.z*v2.z + v2.w*v2.w
                         + v3.x*v3.x + v3.y*v3.y + v3.z*v3.z + v3.w*v3.w;
                ss += __shfl_xor(ss, 1, 64);
                ss += __shfl_xor(ss, 2, 64);
                ss += __shfl_xor(ss, 4, 64);
                float sc = 1.0f / fmaxf(sqrtf(ss), EPSN);

                union { _Float16 h[8]; uint4 u; } pa, pb;
                pa.h[0]=(_Float16)(v0.x*sc); pa.h[1]=(_Float16)(v0.y*sc);
                pa.h[2]=(_Float16)(v0.z*sc); pa.h[3]=(_Float16)(v0.w*sc);
                pa.h[4]=(_Float16)(v1.x*sc); pa.h[5]=(_Float16)(v1.y*sc);
                pa.h[6]=(_Float16)(v1.z*sc); pa.h[7]=(_Float16)(v1.w*sc);
                pb.h[0]=(_Float16)(v2.x*sc); pb.h[1]=(_Float16)(v2.y*sc);
                pb.h[2]=(_Float16)(v2.z*sc); pb.h[3]=(_Float16)(v2.w*sc);
                pb.h[4]=(_Float16)(v3.x*sc); pb.h[5]=(_Float16)(v3.y*sc);
                pb.h[6]=(_Float16)(v3.z*sc); pb.h[7]=(_Float16)(v3.w*sc);

                int cb = r >> 4, cc = r & 15;
                int f  = L >> 1;
                int mA = (L * 2) & 3;
                int mB = (L * 2 + 1) & 3;
                ldsP[(cb * 4 + f) * 64 + (cc | (mA << 4))] = pa.u;
                ldsP[(cb * 4 + f) * 64 + (cc | (mB << 4))] = pb.u;
            }
        }
    }
    __syncthreads();

    // ---- compute ----
    int wave  = tid >> 6, lane = tid & 63;
    int wbase = wave * 256;

    #pragma unroll 1
    for (int bg = 0; bg < 4; ++bg) {
        // register-cache X fragments for 4 b-tiles (64 b's)
        uint4 xf[4][4];
        #pragma unroll
        for (int bt = 0; bt < 4; ++bt)
            #pragma unroll
            for (int f = 0; f < 4; ++f)
                xf[bt][f] = xfrag[((wave * 16 + bg * 4 + bt) * 4 + f) * 64 + lane];

        float s4[4] = {0.f, 0.f, 0.f, 0.f};

        #pragma unroll 1
        for (int cb = 0; cb < CCHUNK / 16; ++cb) {
            uint4 a[4];
            #pragma unroll
            for (int f = 0; f < 4; ++f)
                a[f] = ldsP[(cb * 4 + f) * 64 + lane];

            #pragma unroll
            for (int bt = 0; bt < 4; ++bt) {
                floatx4 acc = {0.f, 0.f, 0.f, 0.f};
                #pragma unroll
                for (int f = 0; f < 4; ++f) {
                    U16 ua, ub;
                    ua.u = a[f];
                    ub.u = xf[bt][f];
                    acc = __builtin_amdgcn_mfma_f32_16x16x32_f16(ua.h, ub.h, acc, 0, 0, 0);
                }
                // e = w_b * exp(2S); w_b factored out until the end
                s4[bt] += __expf(2.0f * acc[0]) + __expf(2.0f * acc[1])
                        + __expf(2.0f * acc[2]) + __expf(2.0f * acc[3]);
            }
        }

        #pragma unroll
        for (int bt = 0; bt < 4; ++bt) {
            float v = s4[bt];
            v += __shfl_xor(v, 16, 64);   // combine the 4 row-groups (c's)
            v += __shfl_xor(v, 32, 64);
            int bidx = wbase + (bg * 4 + bt) * 16 + (lane & 15);
            float wb = w[bidx];
            if (lane < 16) atomicAdd(&negsum[bidx], v * wb);
        }
    }
}

// ---------------------------------------------------------------------------
// Finalize: loss = mean_b [ log(negsum[b] - exp(-posd[b])) + posd[b] ]
// ---------------------------------------------------------------------------
__global__ __launch_bounds__(1024) void final_kernel(
    const float* __restrict__ negsum, const float* __restrict__ posd,
    float* __restrict__ out)
{
    __shared__ float red[1024];
    int t = threadIdx.x;
    float pd = posd[t];
    float term = logf(negsum[t] - __expf(-pd)) + pd;
    red[t] = term;
    __syncthreads();
    #pragma unroll
    for (int s = 512; s > 0; s >>= 1) {
        if (t < s) red[t] += red[t + s];
        __syncthreads();
    }
    if (t == 0) out[0] = red[0] * (1.0f / 1024.0f);
}

extern "C" void kernel_launch(void* const* d_in, const int* in_sizes, int n_in,
                              void* d_out, int out_size, void* d_ws, size_t ws_size,
                              hipStream_t stream)
{
    const float* xs      = (const float*)d_in[0];
    const int*   ys      = (const int*)d_in[1];
    const float* proxies = (const float*)d_in[2];

    char* ws = (char*)d_ws;
    unsigned int* xfrag = (unsigned int*)ws;                 // 256 KB (1024*128 fp16)
    float* w      = (float*)(ws + 262144);                   // 4 KB
    float* posd   = (float*)(ws + 262144 + 4096);            // 4 KB
    float* negsum = (float*)(ws + 262144 + 8192);            // 4 KB

    prep_kernel<<<256, 256, 0, stream>>>(xs, ys, proxies, xfrag, w, posd, negsum);
    main_kernel<<<NBLK_MAIN, 256, 0, stream>>>(proxies, (const uint4*)ws, w, negsum);
    final_kernel<<<1, 1024, 0, stream>>>(negsum, posd, (float*)d_out);
}

// Round 2
// 122.394 us; speedup vs baseline: 1.2951x; 1.2951x over previous
//
#include <hip/hip_runtime.h>
#include <hip/hip_fp16.h>

#define B_N 1024
#define D_K 128
#define C_N 100000
#define CCHUNK 80            // 1250 * 80 == 100000 exactly, multiple of 16
#define NCC 1250
#define BSPLIT 2             // each main block handles 512 b's
#define NBLK_MAIN (NCC * BSPLIT)
#define NREP 8               // negsum replicas to cut atomic contention
#define EPSN 1e-12f

typedef _Float16 half8 __attribute__((ext_vector_type(8)));
typedef float floatx4 __attribute__((ext_vector_type(4)));

union U16 { uint4 u; half8 h; };

__device__ __forceinline__ unsigned int pack2h(float a, float b) {
    union { _Float16 h[2]; unsigned int u; } p;
    p.h[0] = (_Float16)a; p.h[1] = (_Float16)b;
    return p.u;
}

// ---------------------------------------------------------------------------
// Prep: per-row ||x||^2, w[b]=exp(-||x||^2-1), xs -> fp16 fragment-order
// (scaled by 2 so main's S = 2*x.p_hat directly), exact fp32 positive
// distance posd[b], zero negsum replicas. One wave per row b.
// ---------------------------------------------------------------------------
__global__ __launch_bounds__(256) void prep_kernel(
    const float* __restrict__ xs, const int* __restrict__ ys,
    const float* __restrict__ proxies,
    unsigned int* __restrict__ xfrag, float* __restrict__ w,
    float* __restrict__ posd, float* __restrict__ negsumR)
{
    int tid  = threadIdx.x;
    int gid  = blockIdx.x * 256 + tid;
    if (gid < B_N * NREP) negsumR[gid] = 0.0f;

    int wave = tid >> 6, lane = tid & 63;
    int b = blockIdx.x * 4 + wave;   // grid = 256 blocks -> b in [0,1024)

    const float2 xv = ((const float2*)(xs + (size_t)b * D_K))[lane];
    float ss = xv.x * xv.x + xv.y * xv.y;
    #pragma unroll
    for (int m = 1; m < 64; m <<= 1) ss += __shfl_xor(ss, m, 64);
    float xsq = ss;

    // fragment-order write of 2*x: element (b, k=2*lane, 2*lane+1)
    {
        int f  = lane >> 4;
        int m4 = (lane >> 2) & 3;
        int j  = lane & 3;
        int idx = ((((b >> 4) * 4 + f) * 64) + ((b & 15) | (m4 << 4))) * 4 + j;
        xfrag[idx] = pack2h(2.0f * xv.x, 2.0f * xv.y);
    }

    // positive proxy: exact fp32 dot + norm
    int y = ys[b];
    const float2 pv = ((const float2*)(proxies + (size_t)y * D_K))[lane];
    float dt = xv.x * pv.x + xv.y * pv.y;
    float pp = pv.x * pv.x + pv.y * pv.y;
    #pragma unroll
    for (int m = 1; m < 64; m <<= 1) {
        dt += __shfl_xor(dt, m, 64);
        pp += __shfl_xor(pp, m, 64);
    }
    if (lane == 0) {
        w[b] = __expf(-xsq - 1.0f);
        float nrm = fmaxf(sqrtf(pp), EPSN);
        posd[b] = xsq + 1.0f - 2.0f * (dt / nrm);
    }
}

// ---------------------------------------------------------------------------
// Main: block = (c-chunk of 80, b-half of 512). Stage+normalize 80 proxy
// rows into LDS (A-frag order), wave w owns 128 b's (2 b-groups of 64).
// S = 2*x.p_hat via mfma_f32_16x16x32_f16; accumulate sum_c exp(S) per b,
// scale by w[b], atomicAdd into striped negsum replica.
// ---------------------------------------------------------------------------
__global__ __launch_bounds__(256, 4) void main_kernel(
    const float* __restrict__ proxies,
    const uint4* __restrict__ xfrag,
    const float* __restrict__ w,
    float* __restrict__ negsumR)
{
    __shared__ uint4 ldsP[CCHUNK * 8];   // 80 rows * 128 k * 2B = 20 KB

    int tid = threadIdx.x;
    int bx  = blockIdx.x;
    int cc  = bx >> 1;          // c-chunk id (adjacent blocks share -> L2 hit)
    int bs  = bx & 1;           // b-half id
    int c0  = cc * CCHUNK;

    // ---- stage + normalize: 8 lanes per row, 32 rows per pass ----
    {
        int L  = tid & 7;        // lane within row: covers k = L*16 .. L*16+15
        int rb = tid >> 3;       // 0..31
        #pragma unroll 1
        for (int pass = 0; pass < 3; ++pass) {
            int r = pass * 32 + rb;
            if (r < CCHUNK) {
                const float4* src = (const float4*)(proxies + (size_t)(c0 + r) * D_K + L * 16);
                float4 v0 = src[0], v1 = src[1], v2 = src[2], v3 = src[3];
                float ss = v0.x*v0.x + v0.y*v0.y + v0.z*v0.z + v0.w*v0.w
                         + v1.x*v1.x + v1.y*v1.y + v1.z*v1.z + v1.w*v1.w
                         + v2.x*v2.x + v2.y*v2.y + v2.z*v2.z + v2.w*v2.w
                         + v3.x*v3.x + v3.y*v3.y + v3.z*v3.z + v3.w*v3.w;
                ss += __shfl_xor(ss, 1, 64);
                ss += __shfl_xor(ss, 2, 64);
                ss += __shfl_xor(ss, 4, 64);
                float sc = 1.0f / fmaxf(sqrtf(ss), EPSN);

                union { _Float16 h[8]; uint4 u; } pa, pb;
                pa.h[0]=(_Float16)(v0.x*sc); pa.h[1]=(_Float16)(v0.y*sc);
                pa.h[2]=(_Float16)(v0.z*sc); pa.h[3]=(_Float16)(v0.w*sc);
                pa.h[4]=(_Float16)(v1.x*sc); pa.h[5]=(_Float16)(v1.y*sc);
                pa.h[6]=(_Float16)(v1.z*sc); pa.h[7]=(_Float16)(v1.w*sc);
                pb.h[0]=(_Float16)(v2.x*sc); pb.h[1]=(_Float16)(v2.y*sc);
                pb.h[2]=(_Float16)(v2.z*sc); pb.h[3]=(_Float16)(v2.w*sc);
                pb.h[4]=(_Float16)(v3.x*sc); pb.h[5]=(_Float16)(v3.y*sc);
                pb.h[6]=(_Float16)(v3.z*sc); pb.h[7]=(_Float16)(v3.w*sc);

                int cb = r >> 4, rc = r & 15;
                int f  = L >> 1;
                int mA = (L * 2) & 3;
                int mB = (L * 2 + 1) & 3;
                ldsP[(cb * 4 + f) * 64 + (rc | (mA << 4))] = pa.u;
                ldsP[(cb * 4 + f) * 64 + (rc | (mB << 4))] = pb.u;
            }
        }
    }
    __syncthreads();

    // ---- compute ----
    int wave  = tid >> 6, lane = tid & 63;
    int b0    = bs * 512 + wave * 128;       // this wave's 128 b's
    int t0    = b0 >> 4;                     // first 16-b tile index
    float* nsr = negsumR + (size_t)(bx & (NREP - 1)) * B_N;

    #pragma unroll 1
    for (int bg = 0; bg < 2; ++bg) {
        // register-cache X fragments for 4 b-tiles (64 b's)
        uint4 xf[4][4];
        #pragma unroll
        for (int bt = 0; bt < 4; ++bt)
            #pragma unroll
            for (int f = 0; f < 4; ++f)
                xf[bt][f] = xfrag[((t0 + bg * 4 + bt) * 4 + f) * 64 + lane];

        float s4[4] = {0.f, 0.f, 0.f, 0.f};

        #pragma unroll 1
        for (int cb = 0; cb < CCHUNK / 16; ++cb) {
            uint4 a[4];
            #pragma unroll
            for (int f = 0; f < 4; ++f)
                a[f] = ldsP[(cb * 4 + f) * 64 + lane];

            #pragma unroll
            for (int bt = 0; bt < 4; ++bt) {
                floatx4 acc = {0.f, 0.f, 0.f, 0.f};
                #pragma unroll
                for (int f = 0; f < 4; ++f) {
                    U16 ua, ub;
                    ua.u = a[f];
                    ub.u = xf[bt][f];
                    acc = __builtin_amdgcn_mfma_f32_16x16x32_f16(ua.h, ub.h, acc, 0, 0, 0);
                }
                // S already = 2*x.p_hat (x pre-scaled); w_b factored out
                s4[bt] += __expf(acc[0]) + __expf(acc[1])
                        + __expf(acc[2]) + __expf(acc[3]);
            }
        }

        #pragma unroll
        for (int bt = 0; bt < 4; ++bt) {
            float v = s4[bt];
            v += __shfl_xor(v, 16, 64);   // combine the 4 row-groups (c's)
            v += __shfl_xor(v, 32, 64);
            if (lane < 16) {
                int bidx = b0 + bg * 64 + bt * 16 + lane;
                atomicAdd(&nsr[bidx], v * w[bidx]);
            }
        }
    }
}

// ---------------------------------------------------------------------------
// Finalize: loss = mean_b [ log(sum_r negsumR[r][b] - exp(-posd[b])) + posd[b] ]
// ---------------------------------------------------------------------------
__global__ __launch_bounds__(1024) void final_kernel(
    const float* __restrict__ negsumR, const float* __restrict__ posd,
    float* __restrict__ out)
{
    __shared__ float red[1024];
    int t = threadIdx.x;
    float ns = 0.0f;
    #pragma unroll
    for (int r = 0; r < NREP; ++r) ns += negsumR[r * B_N + t];
    float pd = posd[t];
    red[t] = logf(ns - __expf(-pd)) + pd;
    __syncthreads();
    #pragma unroll
    for (int s = 512; s > 0; s >>= 1) {
        if (t < s) red[t] += red[t + s];
        __syncthreads();
    }
    if (t == 0) out[0] = red[0] * (1.0f / 1024.0f);
}

extern "C" void kernel_launch(void* const* d_in, const int* in_sizes, int n_in,
                              void* d_out, int out_size, void* d_ws, size_t ws_size,
                              hipStream_t stream)
{
    const float* xs      = (const float*)d_in[0];
    const int*   ys      = (const int*)d_in[1];
    const float* proxies = (const float*)d_in[2];

    char* ws = (char*)d_ws;
    unsigned int* xfrag = (unsigned int*)ws;                 // 256 KB (1024*128 fp16)
    float* w       = (float*)(ws + 262144);                  // 4 KB
    float* posd    = (float*)(ws + 262144 + 4096);           // 4 KB
    float* negsumR = (float*)(ws + 262144 + 8192);           // 32 KB (8 replicas)

    prep_kernel<<<256, 256, 0, stream>>>(xs, ys, proxies, xfrag, w, posd, negsumR);
    main_kernel<<<NBLK_MAIN, 256, 0, stream>>>(proxies, (const uint4*)ws, w, negsumR);
    final_kernel<<<1, 1024, 0, stream>>>(negsumR, posd, (float*)d_out);
}